// Round 2
// baseline (1893.870 us; speedup 1.0000x reference)
//
#include <hip/hip_runtime.h>
#include <math.h>

// x is [L][B] float32 row-major. out[b] = sum_i sigmoid(max_{j>=i} x[j][b]).
// sigmoid is monotonic => scan raw x, apply sigmoid at the end.
constexpr int L = 8192;
constexpr int B = 4096;
constexpr int ROWS = 64;              // rows per chunk (register-resident)
constexpr int NC = L / ROWS;          // 128 chunks
constexpr int TPB = 256;
constexpr int STRIP = TPB;            // 256 cols per block (1 col/thread)
constexpr int NSTRIP = B / STRIP;     // 16 column strips
constexpr int NBLK = NC * NSTRIP;     // 2048 blocks
constexpr int PAD = 8;                // pad rows below rc=0 (flag=2, incl=-inf)
constexpr int WALK = 8;               // lookback batch width

__device__ __forceinline__ float fast_sigmoid(float t) {
    return __builtin_amdgcn_rcpf(1.0f + __expf(-t));
}

// Re-initialize lookback state every call (ws is poisoned once, never re-poisoned).
__global__ void soft_len_init(int* __restrict__ flags, float* __restrict__ incl) {
    int i = blockIdx.x * blockDim.x + threadIdx.x;
    constexpr int NFLAGS = (NC + PAD) * NSTRIP;
    if (i < NFLAGS) flags[i] = (i < PAD * NSTRIP) ? 2 : 0;   // pad rows: inclusive
    if (i < PAD * B) incl[i] = -INFINITY;                    // pad incl values
}

// Single-pass chained scan. rc = reverse chunk index (rc=0 is the LAST chunk,
// mapped to the lowest blockIdx so lookback waits only on earlier-dispatched
// blocks — same ordering assumption rocPRIM's scan relies on).
__global__ __launch_bounds__(TPB) void soft_len_scan(
        const float* __restrict__ x,
        float* __restrict__ agg,     // [(NC+PAD)][B], rows 0..PAD-1 unused
        float* __restrict__ incl,    // [(NC+PAD)][B], rows 0..PAD-1 = -inf
        float* __restrict__ partial, // [NC][B]
        int*   __restrict__ flags)   // [(NC+PAD)][NSTRIP]
{
    const int rc  = blockIdx.x / NSTRIP;
    const int s   = blockIdx.x % NSTRIP;
    const int c   = NC - 1 - rc;                 // actual chunk
    const int col = s * STRIP + threadIdx.x;
    const float* xin = x + (size_t)c * ROWS * B + col;

    // Load chunk into registers (64 independent coalesced loads).
    float v[ROWS];
    #pragma unroll
    for (int r = 0; r < ROWS; ++r) v[r] = xin[(size_t)r * B];

    float a = v[0];
    #pragma unroll
    for (int r = 1; r < ROWS; ++r) a = fmaxf(a, v[r]);

    // Publish aggregate (or inclusive, for rc==0) ASAP — never blocks.
    if (rc == 0) {
        __hip_atomic_store(&incl[(size_t)(rc + PAD) * B + col], a,
                           __ATOMIC_RELAXED, __HIP_MEMORY_SCOPE_AGENT);
        __threadfence();
        __syncthreads();
        if (threadIdx.x == 0)
            __hip_atomic_store(&flags[(rc + PAD) * NSTRIP + s], 2,
                               __ATOMIC_RELEASE, __HIP_MEMORY_SCOPE_AGENT);
    } else {
        __hip_atomic_store(&agg[(size_t)(rc + PAD) * B + col], a,
                           __ATOMIC_RELAXED, __HIP_MEMORY_SCOPE_AGENT);
        __threadfence();
        __syncthreads();
        if (threadIdx.x == 0)
            __hip_atomic_store(&flags[(rc + PAD) * NSTRIP + s], 1,
                               __ATOMIC_RELEASE, __HIP_MEMORY_SCOPE_AGENT);
    }

    // Lookback: carry = max of aggregates of all rc' < rc. Batched WALK-wide;
    // max is idempotent so combining rows below an inclusive record is safe.
    float carry = -INFINITY;
    if (rc > 0) {
        int j = rc - 1;
        bool done = false;
        while (!done) {
            const int lo = j - (WALK - 1);       // may dip into pad rows
            int st[WALK];
            bool ready;
            do {
                ready = true;
                #pragma unroll
                for (int w = 0; w < WALK; ++w) {
                    st[w] = __hip_atomic_load(&flags[(lo + w + PAD) * NSTRIP + s],
                                              __ATOMIC_ACQUIRE, __HIP_MEMORY_SCOPE_AGENT);
                    ready = ready && (st[w] != 0);
                }
                if (!ready) __builtin_amdgcn_s_sleep(2);
            } while (!ready);

            float val[WALK];
            #pragma unroll
            for (int w = 0; w < WALK; ++w) {
                const float* src = (st[w] == 2) ? incl : agg;
                val[w] = __hip_atomic_load(&src[(size_t)(lo + w + PAD) * B + col],
                                           __ATOMIC_RELAXED, __HIP_MEMORY_SCOPE_AGENT);
            }
            #pragma unroll
            for (int w = 0; w < WALK; ++w) {
                carry = fmaxf(carry, val[w]);
                done = done || (st[w] == 2);
            }
            j -= WALK;
        }

        // Publish inclusive suffix max so later chunks short-circuit.
        __hip_atomic_store(&incl[(size_t)(rc + PAD) * B + col], fmaxf(carry, a),
                           __ATOMIC_RELAXED, __HIP_MEMORY_SCOPE_AGENT);
        __threadfence();
        __syncthreads();
        if (threadIdx.x == 0)
            __hip_atomic_store(&flags[(rc + PAD) * NSTRIP + s], 2,
                               __ATOMIC_RELEASE, __HIP_MEMORY_SCOPE_AGENT);
    }

    // Reverse running max + sigmoid accumulate, all in registers.
    float tail = carry, sum = 0.f;
    #pragma unroll
    for (int r = ROWS - 1; r >= 0; --r) {
        tail = fmaxf(tail, v[r]);
        sum += fast_sigmoid(tail);
    }
    partial[(size_t)rc * B + col] = sum;
}

__global__ __launch_bounds__(TPB) void soft_len_reduce(
        const float* __restrict__ partial, float* __restrict__ out) {
    const int col = blockIdx.x * TPB + threadIdx.x;
    float sum = 0.f;
    #pragma unroll 32
    for (int rc = 0; rc < NC; ++rc) sum += partial[(size_t)rc * B + col];
    out[col] = sum;
}

extern "C" void kernel_launch(void* const* d_in, const int* in_sizes, int n_in,
                              void* d_out, int out_size, void* d_ws, size_t ws_size,
                              hipStream_t stream) {
    const float* x = (const float*)d_in[0];
    float* out = (float*)d_out;

    // Workspace layout (all regions rewritten or re-inited every call):
    float* agg     = (float*)d_ws;                       // (NC+PAD)*B
    float* incl    = agg  + (size_t)(NC + PAD) * B;      // (NC+PAD)*B
    float* partial = incl + (size_t)(NC + PAD) * B;      // NC*B
    int*   flags   = (int*)(partial + (size_t)NC * B);   // (NC+PAD)*NSTRIP

    soft_len_init<<<128, TPB, 0, stream>>>(flags, incl);
    soft_len_scan<<<NBLK, TPB, 0, stream>>>(x, agg, incl, partial, flags);
    soft_len_reduce<<<B / TPB, TPB, 0, stream>>>(partial, out);
}

// Round 3
// 85.315 us; speedup vs baseline: 22.1986x; 22.1986x over previous
//
#include <hip/hip_runtime.h>
#include <math.h>

// x is [L][B] float32 row-major. out[b] = sum_i sigmoid(max_{j>=i} x[j][b]).
// sigmoid is monotonic => cummax(sigmoid(x)) == sigmoid(cummax(x)): scan raw x.
constexpr int L = 8192;
constexpr int B = 4096;
constexpr int CH = 64;            // rows per chunk
constexpr int NC = L / CH;        // 128 chunks
constexpr int TPB = 256;
constexpr int VEC = 4;            // cols per thread (float4)
constexpr int COLS_PER_BLOCK = TPB * VEC;     // 1024
constexpr int COL_TILES = B / COLS_PER_BLOCK; // 4

__device__ __forceinline__ float fast_sigmoid(float t) {
    return __builtin_amdgcn_rcpf(1.0f + __expf(-t));
}

// Pass 1: cmax[c][b] = max over rows of chunk c of x[row][b]. HBM-bound.
__global__ __launch_bounds__(TPB) void soft_len_chunk_max(
        const float* __restrict__ x, float* __restrict__ cmax) {
    const int chunk = blockIdx.x;
    const int col = blockIdx.y * COLS_PER_BLOCK + threadIdx.x * VEC;
    const float4* xin =
        reinterpret_cast<const float4*>(x + (size_t)chunk * CH * B + col);
    float4 m = make_float4(-INFINITY, -INFINITY, -INFINITY, -INFINITY);
    #pragma unroll 16
    for (int r = 0; r < CH; ++r) {
        float4 v = xin[(size_t)r * (B / VEC)];
        m.x = fmaxf(m.x, v.x);
        m.y = fmaxf(m.y, v.y);
        m.z = fmaxf(m.z, v.z);
        m.w = fmaxf(m.w, v.w);
    }
    *reinterpret_cast<float4*>(cmax + (size_t)chunk * B + col) = m;
}

// Pass 2: exclusive suffix max across chunks, per column.
// KEY FIX vs round 1: load ALL NC values into registers first (independent,
// pipelined loads) instead of a 128-deep dependent load->store chain.
__global__ __launch_bounds__(TPB) void soft_len_suffix_max(
        float* __restrict__ cmax) {
    const int col = blockIdx.x * TPB + threadIdx.x;  // 16 blocks x 256
    float v[NC];
    #pragma unroll
    for (int c = 0; c < NC; ++c) v[c] = cmax[(size_t)c * B + col];
    float run = -INFINITY;
    #pragma unroll
    for (int c = NC - 1; c >= 0; --c) {
        float cur = v[c];
        cmax[(size_t)c * B + col] = run;   // exclusive suffix (max of chunks > c)
        run = fmaxf(run, cur);
    }
}

// Pass 3: re-read chunk (Infinity-Cache-warm), reverse running max seeded with
// the carry, accumulate sigmoid per element.
__global__ __launch_bounds__(TPB) void soft_len_chunk_scan(
        const float* __restrict__ x, const float* __restrict__ carry,
        float* __restrict__ partial) {
    const int chunk = blockIdx.x;
    const int col = blockIdx.y * COLS_PER_BLOCK + threadIdx.x * VEC;
    const float4* xin =
        reinterpret_cast<const float4*>(x + (size_t)chunk * CH * B + col);
    float4 tail = *reinterpret_cast<const float4*>(carry + (size_t)chunk * B + col);
    float4 sum = make_float4(0.f, 0.f, 0.f, 0.f);
    #pragma unroll 8
    for (int r = CH - 1; r >= 0; --r) {
        float4 v = xin[(size_t)r * (B / VEC)];
        tail.x = fmaxf(tail.x, v.x);
        tail.y = fmaxf(tail.y, v.y);
        tail.z = fmaxf(tail.z, v.z);
        tail.w = fmaxf(tail.w, v.w);
        sum.x += fast_sigmoid(tail.x);
        sum.y += fast_sigmoid(tail.y);
        sum.z += fast_sigmoid(tail.z);
        sum.w += fast_sigmoid(tail.w);
    }
    *reinterpret_cast<float4*>(partial + (size_t)chunk * B + col) = sum;
}

// Pass 4: out[b] = sum over chunks of partial[c][b]. Register-array load like
// pass 2 (independent loads), then one add tree.
__global__ __launch_bounds__(TPB) void soft_len_reduce(
        const float* __restrict__ partial, float* __restrict__ out) {
    const int col = blockIdx.x * TPB + threadIdx.x;
    float s = 0.f;
    #pragma unroll
    for (int c = 0; c < NC; ++c) s += partial[(size_t)c * B + col];
    out[col] = s;
}

extern "C" void kernel_launch(void* const* d_in, const int* in_sizes, int n_in,
                              void* d_out, int out_size, void* d_ws, size_t ws_size,
                              hipStream_t stream) {
    const float* x = (const float*)d_in[0];
    float* out = (float*)d_out;

    // Workspace: cmax [NC][B] (2 MiB), partial [NC][B] (2 MiB).
    // Both fully overwritten every call before any read (poison-safe).
    float* cmax = (float*)d_ws;
    float* partial = cmax + (size_t)NC * B;

    dim3 gbig(NC, COL_TILES);  // (128, 4) = 512 blocks, 2 per CU
    soft_len_chunk_max<<<gbig, TPB, 0, stream>>>(x, cmax);
    soft_len_suffix_max<<<B / TPB, TPB, 0, stream>>>(cmax);
    soft_len_chunk_scan<<<gbig, TPB, 0, stream>>>(x, cmax, partial);
    soft_len_reduce<<<B / TPB, TPB, 0, stream>>>(partial, out);
}